// Round 1
// baseline (1750.481 us; speedup 1.0000x reference)
//
#include <hip/hip_runtime.h>
#include <math.h>

#define D_MODEL 1024
#define NHEADS 16
#define DK 64
#define SEQ 2048
#define BATCH 2

// ---------------------------------------------------------------------------
// NT GEMM: C[m,n] = sum_k A[m,k] * B[n,k]   (A: MxK, B: NxK, C: MxN, row-major)
// 128x128 tile, BK=8, 256 threads, 8x8 micro-tile per thread. fp32.
// ---------------------------------------------------------------------------
#define BM 128
#define BN 128
#define BK 8

__global__ __launch_bounds__(256)
void gemm_nt(const float* __restrict__ A, const float* __restrict__ B,
             float* __restrict__ C, int M, int N, int K) {
  __shared__ float As[BK][BM];
  __shared__ float Bs[BK][BN];
  const int tid = threadIdx.x;
  const int m0 = blockIdx.y * BM;
  const int n0 = blockIdx.x * BN;
  const int tx = tid & 15;        // col group
  const int ty = tid >> 4;        // row group
  const int lrow = tid >> 1;      // 0..127 (load row)
  const int lk4  = (tid & 1) * 4; // 0 or 4 (k offset)

  float acc[8][8];
  #pragma unroll
  for (int i = 0; i < 8; ++i)
    #pragma unroll
    for (int j = 0; j < 8; ++j) acc[i][j] = 0.f;

  for (int k0 = 0; k0 < K; k0 += BK) {
    float4 av = *(const float4*)(A + (size_t)(m0 + lrow) * K + k0 + lk4);
    float4 bv = *(const float4*)(B + (size_t)(n0 + lrow) * K + k0 + lk4);
    As[lk4 + 0][lrow] = av.x; As[lk4 + 1][lrow] = av.y;
    As[lk4 + 2][lrow] = av.z; As[lk4 + 3][lrow] = av.w;
    Bs[lk4 + 0][lrow] = bv.x; Bs[lk4 + 1][lrow] = bv.y;
    Bs[lk4 + 2][lrow] = bv.z; Bs[lk4 + 3][lrow] = bv.w;
    __syncthreads();
    #pragma unroll
    for (int kk = 0; kk < BK; ++kk) {
      float a[8], b[8];
      *(float4*)&a[0] = *(const float4*)&As[kk][ty * 8];
      *(float4*)&a[4] = *(const float4*)&As[kk][ty * 8 + 4];
      *(float4*)&b[0] = *(const float4*)&Bs[kk][tx * 8];
      *(float4*)&b[4] = *(const float4*)&Bs[kk][tx * 8 + 4];
      #pragma unroll
      for (int i = 0; i < 8; ++i)
        #pragma unroll
        for (int j = 0; j < 8; ++j)
          acc[i][j] = fmaf(a[i], b[j], acc[i][j]);
    }
    __syncthreads();
  }

  #pragma unroll
  for (int i = 0; i < 8; ++i) {
    float* crow = C + (size_t)(m0 + ty * 8 + i) * N + n0 + tx * 8;
    float4 c0 = {acc[i][0], acc[i][1], acc[i][2], acc[i][3]};
    float4 c1 = {acc[i][4], acc[i][5], acc[i][6], acc[i][7]};
    *(float4*)(crow)     = c0;
    *(float4*)(crow + 4) = c1;
  }
}

// ---------------------------------------------------------------------------
// RoPE (in-place on Q and K, layout [B, S, H*DK]).
// pair i in 0..31: freq = theta^(-i/32); rotate (x[2i], x[2i+1]).
// ---------------------------------------------------------------------------
__global__ void rope_kernel(float* __restrict__ Q, float* __restrict__ K,
                            const int* __restrict__ pos, int total) {
  int idx = blockIdx.x * blockDim.x + threadIdx.x;
  if (idx >= total) return;
  int i = idx & 31;             // pair index
  int h = (idx >> 5) & (NHEADS - 1);
  int s = (idx >> 9) & (SEQ - 1);
  int b = idx >> 20;            // 32*16*2048 = 2^20
  float p = (float)pos[b * SEQ + s];
  // theta^(-i/32) = exp(-i * ln(10000)/32)
  float freq = expf(-(float)i * 0.2878231366242558f);
  float ang = p * freq;
  float sn, cs;
  sincosf(ang, &sn, &cs);
  size_t base = ((size_t)(b * SEQ + s)) * D_MODEL + h * DK + 2 * i;
  float2 q = *(float2*)(Q + base);
  float2 k = *(float2*)(K + base);
  float2 qo = {q.x * cs - q.y * sn, q.x * sn + q.y * cs};
  float2 ko = {k.x * cs - k.y * sn, k.x * sn + k.y * cs};
  *(float2*)(Q + base) = qo;
  *(float2*)(K + base) = ko;
}

// ---------------------------------------------------------------------------
// Causal attention, flash-style online softmax.
// Layouts: Q,K,V,O all [B, S, H*DK]. Grid: (S/TQ, H, B), block = 1024 (16 waves).
// Wave w handles query row q0+w. K/V tiles of 64 keys staged in LDS.
// Scores: lane-per-key (padded stride 68 -> conflict-free b128).
// PV: lane-per-dim, P broadcast from per-wave LDS row.
// ---------------------------------------------------------------------------
#define TQ 16
#define TKEY 64

__device__ inline float wave_max(float v) {
  #pragma unroll
  for (int o = 32; o > 0; o >>= 1) v = fmaxf(v, __shfl_xor(v, o));
  return v;
}
__device__ inline float wave_sum(float v) {
  #pragma unroll
  for (int o = 32; o > 0; o >>= 1) v += __shfl_xor(v, o);
  return v;
}

__global__ __launch_bounds__(1024)
void attn_kernel(const float* __restrict__ Q, const float* __restrict__ K,
                 const float* __restrict__ V, float* __restrict__ O) {
  __shared__ float Ks[TKEY][68];
  __shared__ float Vs[TKEY][68];
  __shared__ float Qs[TQ][68];
  __shared__ float Ps[TQ][TKEY];

  const int tid = threadIdx.x;
  const int w = tid >> 6, lane = tid & 63;
  const int q0 = blockIdx.x * TQ;
  const int h = blockIdx.y, b = blockIdx.z;
  const int q = q0 + w;
  const size_t bh = (size_t)b * SEQ * D_MODEL + h * DK; // + row*D_MODEL + d

  Qs[w][lane] = Q[bh + (size_t)q * D_MODEL + lane] * 0.125f; // fold 1/sqrt(64)

  float m = -1e30f, lsum = 0.f, acc = 0.f;
  const int qmax = q0 + TQ - 1;
  const int ntiles = qmax / TKEY + 1;
  const int lrow = tid >> 4;           // 0..63
  const int lc4 = (tid & 15) * 4;      // 0..60

  for (int t = 0; t < ntiles; ++t) {
    const int j0 = t * TKEY;
    __syncthreads();
    {
      float4 kv = *(const float4*)(K + bh + (size_t)(j0 + lrow) * D_MODEL + lc4);
      float4 vv = *(const float4*)(V + bh + (size_t)(j0 + lrow) * D_MODEL + lc4);
      *(float4*)&Ks[lrow][lc4] = kv;
      *(float4*)&Vs[lrow][lc4] = vv;
    }
    __syncthreads();

    // score for key j0+lane
    float s = 0.f;
    const float4* kr = (const float4*)&Ks[lane][0];
    const float4* qr = (const float4*)&Qs[w][0];
    #pragma unroll
    for (int d4 = 0; d4 < 16; ++d4) {
      float4 a = qr[d4], kk = kr[d4];
      s += a.x * kk.x + a.y * kk.y + a.z * kk.z + a.w * kk.w;
    }
    if (j0 + lane > q) s = -1e30f;   // causal mask

    float tmax = wave_max(s);
    float mnew = fmaxf(m, tmax);
    float f = __expf(m - mnew);
    float p = __expf(s - mnew);
    lsum = lsum * f + p;
    acc *= f;
    m = mnew;
    Ps[w][lane] = p;                  // per-wave row; wave-ordered DS ops

    #pragma unroll
    for (int j4 = 0; j4 < 16; ++j4) {
      float4 pp = *(const float4*)&Ps[w][j4 * 4];
      acc = fmaf(pp.x, Vs[j4 * 4 + 0][lane], acc);
      acc = fmaf(pp.y, Vs[j4 * 4 + 1][lane], acc);
      acc = fmaf(pp.z, Vs[j4 * 4 + 2][lane], acc);
      acc = fmaf(pp.w, Vs[j4 * 4 + 3][lane], acc);
    }
  }

  float tot = wave_sum(lsum);
  O[bh + (size_t)q * D_MODEL + lane] = acc / tot;
}

// ---------------------------------------------------------------------------
extern "C" void kernel_launch(void* const* d_in, const int* in_sizes, int n_in,
                              void* d_out, int out_size, void* d_ws, size_t ws_size,
                              hipStream_t stream) {
  const float* x  = (const float*)d_in[0];
  const float* Wq = (const float*)d_in[1];
  const float* Wk = (const float*)d_in[2];
  const float* Wv = (const float*)d_in[3];
  const float* Wo = (const float*)d_in[4];
  const int* pos  = (const int*)d_in[5];

  const int M = BATCH * SEQ;      // 4096
  const size_t bufElems = (size_t)M * D_MODEL;  // 4,194,304 floats = 16 MB

  float* ws = (float*)d_ws;
  float* Qb = ws;
  float* Kb = ws + bufElems;
  float* Vb = ws + 2 * bufElems;
  float* Ob = ws + 3 * bufElems;

  dim3 gg(D_MODEL / BN, M / BM);  // (8, 32)
  gemm_nt<<<gg, 256, 0, stream>>>(x, Wq, Qb, M, D_MODEL, D_MODEL);
  gemm_nt<<<gg, 256, 0, stream>>>(x, Wk, Kb, M, D_MODEL, D_MODEL);
  gemm_nt<<<gg, 256, 0, stream>>>(x, Wv, Vb, M, D_MODEL, D_MODEL);

  int totalPairs = BATCH * SEQ * NHEADS * (DK / 2); // 2,097,152
  rope_kernel<<<(totalPairs + 255) / 256, 256, 0, stream>>>(Qb, Kb, pos, totalPairs);

  attn_kernel<<<dim3(SEQ / TQ, NHEADS, BATCH), 1024, 0, stream>>>(Qb, Kb, Vb, Ob);

  gemm_nt<<<gg, 256, 0, stream>>>(Ob, Wo, (float*)d_out, M, D_MODEL, D_MODEL);
}

// Round 3
// 831.425 us; speedup vs baseline: 2.1054x; 2.1054x over previous
//
#include <hip/hip_runtime.h>
#include <math.h>

#define D_MODEL 1024
#define NHEADS 16
#define DK 64
#define SEQ 2048
#define BATCH 2

typedef __attribute__((ext_vector_type(8))) short bfrag8;   // 8 bf16 (4 VGPRs)
typedef __attribute__((ext_vector_type(4))) float f32x4;

// ---------------------------------------------------------------------------
// NT GEMM: C[m,n] = sum_k A[m,k] * B[n,k]  (fp32, unchanged from baseline)
// ---------------------------------------------------------------------------
#define BM 128
#define BN 128
#define BK 8

__global__ __launch_bounds__(256)
void gemm_nt(const float* __restrict__ A, const float* __restrict__ B,
             float* __restrict__ C, int M, int N, int K) {
  __shared__ float As[BK][BM];
  __shared__ float Bs[BK][BN];
  const int tid = threadIdx.x;
  const int m0 = blockIdx.y * BM;
  const int n0 = blockIdx.x * BN;
  const int tx = tid & 15;
  const int ty = tid >> 4;
  const int lrow = tid >> 1;
  const int lk4  = (tid & 1) * 4;

  float acc[8][8];
  #pragma unroll
  for (int i = 0; i < 8; ++i)
    #pragma unroll
    for (int j = 0; j < 8; ++j) acc[i][j] = 0.f;

  for (int k0 = 0; k0 < K; k0 += BK) {
    float4 av = *(const float4*)(A + (size_t)(m0 + lrow) * K + k0 + lk4);
    float4 bv = *(const float4*)(B + (size_t)(n0 + lrow) * K + k0 + lk4);
    As[lk4 + 0][lrow] = av.x; As[lk4 + 1][lrow] = av.y;
    As[lk4 + 2][lrow] = av.z; As[lk4 + 3][lrow] = av.w;
    Bs[lk4 + 0][lrow] = bv.x; Bs[lk4 + 1][lrow] = bv.y;
    Bs[lk4 + 2][lrow] = bv.z; Bs[lk4 + 3][lrow] = bv.w;
    __syncthreads();
    #pragma unroll
    for (int kk = 0; kk < BK; ++kk) {
      float a[8], b[8];
      *(float4*)&a[0] = *(const float4*)&As[kk][ty * 8];
      *(float4*)&a[4] = *(const float4*)&As[kk][ty * 8 + 4];
      *(float4*)&b[0] = *(const float4*)&Bs[kk][tx * 8];
      *(float4*)&b[4] = *(const float4*)&Bs[kk][tx * 8 + 4];
      #pragma unroll
      for (int i = 0; i < 8; ++i)
        #pragma unroll
        for (int j = 0; j < 8; ++j)
          acc[i][j] = fmaf(a[i], b[j], acc[i][j]);
    }
    __syncthreads();
  }

  #pragma unroll
  for (int i = 0; i < 8; ++i) {
    float* crow = C + (size_t)(m0 + ty * 8 + i) * N + n0 + tx * 8;
    float4 c0 = {acc[i][0], acc[i][1], acc[i][2], acc[i][3]};
    float4 c1 = {acc[i][4], acc[i][5], acc[i][6], acc[i][7]};
    *(float4*)(crow)     = c0;
    *(float4*)(crow + 4) = c1;
  }
}

// ---------------------------------------------------------------------------
// RoPE (unchanged)
// ---------------------------------------------------------------------------
__global__ void rope_kernel(float* __restrict__ Q, float* __restrict__ K,
                            const int* __restrict__ pos, int total) {
  int idx = blockIdx.x * blockDim.x + threadIdx.x;
  if (idx >= total) return;
  int i = idx & 31;
  int h = (idx >> 5) & (NHEADS - 1);
  int s = (idx >> 9) & (SEQ - 1);
  int b = idx >> 20;
  float p = (float)pos[b * SEQ + s];
  float freq = expf(-(float)i * 0.2878231366242558f);
  float ang = p * freq;
  float sn, cs;
  sincosf(ang, &sn, &cs);
  size_t base = ((size_t)(b * SEQ + s)) * D_MODEL + h * DK + 2 * i;
  float2 q = *(float2*)(Q + base);
  float2 k = *(float2*)(K + base);
  float2 qo = {q.x * cs - q.y * sn, q.x * sn + q.y * cs};
  float2 ko = {k.x * cs - k.y * sn, k.x * sn + k.y * cs};
  *(float2*)(Q + base) = qo;
  *(float2*)(K + base) = ko;
}

// ---------------------------------------------------------------------------
// MFMA flash attention (bf16 inputs to matrix cores, fp32 softmax/accum).
// Grid: (SEQ/64, H, B), block = 256 (4 waves). Wave w owns 16 query rows.
// LDS: Ks[key][dim] bf16, Vt[dim][key] bf16 (transposed at staging so both
// MFMA B-frags are contiguous b128 reads), Ps per-wave P round-trip (m120).
// Layouts (m89/m91/m120-verified): A/B frag: outer=lane&15, k=quad*8+j;
// C/D: row=quad*4+reg, col=lane&15. Stride 72 bf16 => 2-way bank alias (free).
// R2 fix: PV k-loop steps by 32 (one MFMA consumes K=32), not 16 — the
// 16-step version double-counted keys and read past the Ps row (NaN source).
// ---------------------------------------------------------------------------
#define KSTRIDE 72

__device__ inline short f2bf(float f) {
  union { float f; unsigned u; } c; c.f = f;
  unsigned r = c.u + 0x7FFF + ((c.u >> 16) & 1);   // RNE
  return (short)(r >> 16);
}

__global__ __launch_bounds__(256)
void attn_mfma(const float* __restrict__ Q, const float* __restrict__ K,
               const float* __restrict__ V, float* __restrict__ O) {
  __shared__ short Ks[64 * KSTRIDE];
  __shared__ short Vt[64 * KSTRIDE];
  __shared__ short Ps[4][16 * KSTRIDE];

  const int tid = threadIdx.x;
  const int w = tid >> 6, lane = tid & 63;
  const int l15 = lane & 15, quad = lane >> 4;
  const int qt = blockIdx.x;
  const int h = blockIdx.y, b = blockIdx.z;
  const int q0 = qt * 64;
  const size_t bh = (size_t)b * SEQ * D_MODEL + h * DK;
  const int qrow_base = q0 + w * 16;

  // Q fragment (A-layout), scale 1/sqrt(64) folded, bf16. Loaded once.
  bfrag8 qfrag[2];
  {
    const float* qp = Q + bh + (size_t)(qrow_base + l15) * D_MODEL + quad * 8;
    #pragma unroll
    for (int half = 0; half < 2; ++half) {
      float4 v0 = *(const float4*)(qp + half * 32);
      float4 v1 = *(const float4*)(qp + half * 32 + 4);
      short tmp[8];
      tmp[0] = f2bf(v0.x * 0.125f); tmp[1] = f2bf(v0.y * 0.125f);
      tmp[2] = f2bf(v0.z * 0.125f); tmp[3] = f2bf(v0.w * 0.125f);
      tmp[4] = f2bf(v1.x * 0.125f); tmp[5] = f2bf(v1.y * 0.125f);
      tmp[6] = f2bf(v1.z * 0.125f); tmp[7] = f2bf(v1.w * 0.125f);
      qfrag[half] = *(bfrag8*)tmp;
    }
  }

  float m_r[4], l_r[4];
  f32x4 o_acc[4];
  #pragma unroll
  for (int r = 0; r < 4; ++r) { m_r[r] = -1e30f; l_r[r] = 0.f; o_acc[r] = (f32x4)0.f; }

  const int skey = tid >> 2;       // staging: key row 0..63
  const int sdc  = tid & 3;        // dim chunk of 16

  const int ntiles = qt + 1;
  for (int t = 0; t < ntiles; ++t) {
    const int j0 = t * 64;
    __syncthreads();
    // ---- stage K (row-major bf16) and V (transposed bf16) ----
    {
      const float* kp = K + bh + (size_t)(j0 + skey) * D_MODEL + sdc * 16;
      const float* vp = V + bh + (size_t)(j0 + skey) * D_MODEL + sdc * 16;
      float kf[16], vf[16];
      #pragma unroll
      for (int i = 0; i < 4; ++i) {
        *(float4*)&kf[i * 4] = *(const float4*)(kp + i * 4);
        *(float4*)&vf[i * 4] = *(const float4*)(vp + i * 4);
      }
      short kb[16];
      #pragma unroll
      for (int i = 0; i < 16; ++i) kb[i] = f2bf(kf[i]);
      *(bfrag8*)&Ks[skey * KSTRIDE + sdc * 16]     = *(bfrag8*)&kb[0];
      *(bfrag8*)&Ks[skey * KSTRIDE + sdc * 16 + 8] = *(bfrag8*)&kb[8];
      #pragma unroll
      for (int i = 0; i < 16; ++i)
        Vt[(sdc * 16 + i) * KSTRIDE + skey] = f2bf(vf[i]);
    }
    __syncthreads();

    // ---- QK^T: 4 key-subtiles of 16, two chained MFMAs (dims 0-31, 32-63) ----
    f32x4 sc[4];
    #pragma unroll
    for (int st = 0; st < 4; ++st) {
      bfrag8 kf0 = *(const bfrag8*)&Ks[(st * 16 + l15) * KSTRIDE + quad * 8];
      bfrag8 kf1 = *(const bfrag8*)&Ks[(st * 16 + l15) * KSTRIDE + 32 + quad * 8];
      f32x4 acc = (f32x4)0.f;
      acc = __builtin_amdgcn_mfma_f32_16x16x32_bf16(qfrag[0], kf0, acc, 0, 0, 0);
      acc = __builtin_amdgcn_mfma_f32_16x16x32_bf16(qfrag[1], kf1, acc, 0, 0, 0);
      sc[st] = acc;
    }

    // ---- causal mask (diagonal region only; wave-uniform predicate) ----
    if (j0 + 64 > qrow_base) {
      #pragma unroll
      for (int st = 0; st < 4; ++st) {
        int key = j0 + st * 16 + l15;
        #pragma unroll
        for (int r = 0; r < 4; ++r) {
          int qrow = qrow_base + quad * 4 + r;
          if (key > qrow) sc[st][r] = -1e30f;
        }
      }
    }

    // ---- online softmax per q-row (row = quad*4 + r; 16 cols across l15) ----
    float p_[4][4];
    #pragma unroll
    for (int r = 0; r < 4; ++r) {
      float tm = fmaxf(fmaxf(sc[0][r], sc[1][r]), fmaxf(sc[2][r], sc[3][r]));
      tm = fmaxf(tm, __shfl_xor(tm, 1));
      tm = fmaxf(tm, __shfl_xor(tm, 2));
      tm = fmaxf(tm, __shfl_xor(tm, 4));
      tm = fmaxf(tm, __shfl_xor(tm, 8));
      float mnew = fmaxf(m_r[r], tm);
      float alpha = __expf(m_r[r] - mnew);
      m_r[r] = mnew;
      float rs = 0.f;
      #pragma unroll
      for (int st = 0; st < 4; ++st) { p_[st][r] = __expf(sc[st][r] - mnew); rs += p_[st][r]; }
      rs += __shfl_xor(rs, 1);
      rs += __shfl_xor(rs, 2);
      rs += __shfl_xor(rs, 4);
      rs += __shfl_xor(rs, 8);
      l_r[r] = l_r[r] * alpha + rs;
      #pragma unroll
      for (int n0 = 0; n0 < 4; ++n0) o_acc[n0][r] *= alpha;
    }

    // ---- P round-trip through LDS: C-layout -> A-layout (per-wave buffer) ----
    #pragma unroll
    for (int st = 0; st < 4; ++st)
      #pragma unroll
      for (int r = 0; r < 4; ++r)
        Ps[w][(quad * 4 + r) * KSTRIDE + st * 16 + l15] = f2bf(p_[st][r]);
    __asm__ volatile("s_waitcnt lgkmcnt(0)" ::: "memory");

    // ---- PV: O[16q][64d] += P[16q][64k] * V[64k][64d] ----
    // one MFMA consumes K=32 keys => 2 chunks with base kc*32
    #pragma unroll
    for (int kc = 0; kc < 2; ++kc) {
      bfrag8 afrag = *(const bfrag8*)&Ps[w][l15 * KSTRIDE + kc * 32 + quad * 8];
      #pragma unroll
      for (int n0 = 0; n0 < 4; ++n0) {
        bfrag8 vfrag = *(const bfrag8*)&Vt[(n0 * 16 + l15) * KSTRIDE + kc * 32 + quad * 8];
        o_acc[n0] = __builtin_amdgcn_mfma_f32_16x16x32_bf16(afrag, vfrag, o_acc[n0], 0, 0, 0);
      }
    }
  }

  // ---- epilogue: normalize and store ----
  #pragma unroll
  for (int n0 = 0; n0 < 4; ++n0)
    #pragma unroll
    for (int r = 0; r < 4; ++r) {
      int qrow = qrow_base + quad * 4 + r;
      O[bh + (size_t)qrow * D_MODEL + n0 * 16 + l15] = o_acc[n0][r] / l_r[r];
    }
}

// ---------------------------------------------------------------------------
extern "C" void kernel_launch(void* const* d_in, const int* in_sizes, int n_in,
                              void* d_out, int out_size, void* d_ws, size_t ws_size,
                              hipStream_t stream) {
  const float* x  = (const float*)d_in[0];
  const float* Wq = (const float*)d_in[1];
  const float* Wk = (const float*)d_in[2];
  const float* Wv = (const float*)d_in[3];
  const float* Wo = (const float*)d_in[4];
  const int* pos  = (const int*)d_in[5];

  const int M = BATCH * SEQ;
  const size_t bufElems = (size_t)M * D_MODEL;

  float* ws = (float*)d_ws;
  float* Qb = ws;
  float* Kb = ws + bufElems;
  float* Vb = ws + 2 * bufElems;
  float* Ob = ws + 3 * bufElems;

  dim3 gg(D_MODEL / BN, M / BM);
  gemm_nt<<<gg, 256, 0, stream>>>(x, Wq, Qb, M, D_MODEL, D_MODEL);
  gemm_nt<<<gg, 256, 0, stream>>>(x, Wk, Kb, M, D_MODEL, D_MODEL);
  gemm_nt<<<gg, 256, 0, stream>>>(x, Wv, Vb, M, D_MODEL, D_MODEL);

  int totalPairs = BATCH * SEQ * NHEADS * (DK / 2);
  rope_kernel<<<(totalPairs + 255) / 256, 256, 0, stream>>>(Qb, Kb, pos, totalPairs);

  attn_mfma<<<dim3(SEQ / 64, NHEADS, BATCH), 256, 0, stream>>>(Qb, Kb, Vb, Ob);

  gemm_nt<<<gg, 256, 0, stream>>>(Ob, Wo, (float*)d_out, M, D_MODEL, D_MODEL);
}

// Round 4
// 321.559 us; speedup vs baseline: 5.4437x; 2.5856x over previous
//
#include <hip/hip_runtime.h>
#include <math.h>

#define D_MODEL 1024
#define NHEADS 16
#define DK 64
#define SEQ 2048
#define BATCH 2
#define MROWS (BATCH * SEQ)            // 4096

typedef __attribute__((ext_vector_type(8))) short bfrag8;   // 8 bf16 (4 VGPRs)
typedef __attribute__((ext_vector_type(4))) float f32x4;
typedef unsigned short u16;

#define GLOBAL_AS(p) ((const __attribute__((address_space(1))) void*)(p))
#define LDS_AS(p)    ((__attribute__((address_space(3))) void*)(p))

__device__ inline u16 f2bf(float f) {
  union { float f; unsigned u; } c; c.f = f;
  unsigned r = c.u + 0x7FFF + ((c.u >> 16) & 1);   // RNE
  return (u16)(r >> 16);
}

// ---------------------------------------------------------------------------
// Fused fp32 -> bf16 conversion for x + Wq + Wk + Wv + Wo into one contiguous
// bf16 region: [xb 4M][wq 1M][wk 1M][wv 1M][wo 1M]. One float4 per thread.
// ---------------------------------------------------------------------------
struct CvtPtrs { const float* src[5]; };

__global__ __launch_bounds__(256)
void convert_inputs(CvtPtrs p, u16* __restrict__ dst) {
  size_t base = ((size_t)blockIdx.x * 256 + threadIdx.x) * 4;
  const size_t XSZ = (size_t)MROWS * D_MODEL;              // 4M
  const float* s; size_t off;
  if (base < XSZ) { s = p.src[0]; off = base; }
  else {
    size_t j = base - XSZ;
    s = p.src[1 + (int)(j >> 20)];
    off = j & ((1u << 20) - 1);
  }
  float4 v = *(const float4*)(s + off);
  u16 o[4] = { f2bf(v.x), f2bf(v.y), f2bf(v.z), f2bf(v.w) };
  *(__attribute__((ext_vector_type(4))) u16*)(dst + base) =
      *(__attribute__((ext_vector_type(4))) u16*)o;
}

__global__ __launch_bounds__(256)
void convert_buf(const float* __restrict__ s, u16* __restrict__ dst) {
  size_t base = ((size_t)blockIdx.x * 256 + threadIdx.x) * 4;
  float4 v = *(const float4*)(s + base);
  u16 o[4] = { f2bf(v.x), f2bf(v.y), f2bf(v.z), f2bf(v.w) };
  *(__attribute__((ext_vector_type(4))) u16*)(dst + base) =
      *(__attribute__((ext_vector_type(4))) u16*)o;
}

// ---------------------------------------------------------------------------
// bf16 MFMA NT-GEMM (m97 structure): C[m,n] = sum_k A[m,k]*B[n,k], fp32 C.
// A: MROWSxK row-major bf16, B: N x K row-major bf16. K = N = 1024.
// 128x128 tile, BK=32, 256 threads (4 waves in 2x2), 4x4 16x16 subtiles/wave.
// Staging: global_load_lds width=16, contiguous LDS (no padding — required).
// ---------------------------------------------------------------------------
__device__ inline void gemm_tile_body(const u16* __restrict__ A,
                                      const u16* __restrict__ B,
                                      float* __restrict__ C,
                                      int m0, int n0) {
  __shared__ u16 As[128 * 32];
  __shared__ u16 Bs[128 * 32];

  const int tid = threadIdx.x;
  const int w = tid >> 6, lane = tid & 63;
  const int l15 = lane & 15, quad = lane >> 4;
  const int wm = w >> 1, wn = w & 1;
  const int srow = tid >> 2;          // 0..63  (= w*16 + lane>>2)
  const int scol = (tid & 3) * 8;     // k-offset, 16B chunks

  f32x4 acc[4][4];
  #pragma unroll
  for (int mi = 0; mi < 4; ++mi)
    #pragma unroll
    for (int ni = 0; ni < 4; ++ni) acc[mi][ni] = (f32x4)0.f;

  for (int k0 = 0; k0 < D_MODEL; k0 += 32) {
    __syncthreads();
    #pragma unroll
    for (int i = 0; i < 2; ++i) {
      const u16* ga = A + (size_t)(m0 + i * 64 + srow) * D_MODEL + k0 + scol;
      const u16* gb = B + (size_t)(n0 + i * 64 + srow) * D_MODEL + k0 + scol;
      __builtin_amdgcn_global_load_lds(GLOBAL_AS(ga), LDS_AS(&As[(i * 64 + w * 16) * 32]), 16, 0, 0);
      __builtin_amdgcn_global_load_lds(GLOBAL_AS(gb), LDS_AS(&Bs[(i * 64 + w * 16) * 32]), 16, 0, 0);
    }
    __syncthreads();

    bfrag8 af[4], bfr[4];
    #pragma unroll
    for (int i = 0; i < 4; ++i) {
      af[i]  = *(const bfrag8*)&As[(wm * 64 + i * 16 + l15) * 32 + quad * 8];
      bfr[i] = *(const bfrag8*)&Bs[(wn * 64 + i * 16 + l15) * 32 + quad * 8];
    }
    #pragma unroll
    for (int mi = 0; mi < 4; ++mi)
      #pragma unroll
      for (int ni = 0; ni < 4; ++ni)
        acc[mi][ni] = __builtin_amdgcn_mfma_f32_16x16x32_bf16(af[mi], bfr[ni], acc[mi][ni], 0, 0, 0);
  }

  #pragma unroll
  for (int mi = 0; mi < 4; ++mi)
    #pragma unroll
    for (int ni = 0; ni < 4; ++ni)
      #pragma unroll
      for (int r = 0; r < 4; ++r) {
        int row = m0 + wm * 64 + mi * 16 + quad * 4 + r;
        int col = n0 + wn * 64 + ni * 16 + l15;
        C[(size_t)row * D_MODEL + col] = acc[mi][ni][r];
      }
}

struct QKVPtrs { const u16* W[3]; float* C[3]; };

__global__ __launch_bounds__(256)
void gemm_qkv_bf16(const u16* __restrict__ A, QKVPtrs p) {
  gemm_tile_body(A, p.W[blockIdx.z], p.C[blockIdx.z],
                 blockIdx.y * 128, blockIdx.x * 128);
}

__global__ __launch_bounds__(256)
void gemm_out_bf16(const u16* __restrict__ A, const u16* __restrict__ B,
                   float* __restrict__ C) {
  gemm_tile_body(A, B, C, blockIdx.y * 128, blockIdx.x * 128);
}

// ---------------------------------------------------------------------------
// RoPE (unchanged, fp32 in-place on Q and K)
// ---------------------------------------------------------------------------
__global__ void rope_kernel(float* __restrict__ Q, float* __restrict__ K,
                            const int* __restrict__ pos, int total) {
  int idx = blockIdx.x * blockDim.x + threadIdx.x;
  if (idx >= total) return;
  int i = idx & 31;
  int h = (idx >> 5) & (NHEADS - 1);
  int s = (idx >> 9) & (SEQ - 1);
  int b = idx >> 20;
  float p = (float)pos[b * SEQ + s];
  float freq = expf(-(float)i * 0.2878231366242558f);
  float ang = p * freq;
  float sn, cs;
  sincosf(ang, &sn, &cs);
  size_t base = ((size_t)(b * SEQ + s)) * D_MODEL + h * DK + 2 * i;
  float2 q = *(float2*)(Q + base);
  float2 k = *(float2*)(K + base);
  float2 qo = {q.x * cs - q.y * sn, q.x * sn + q.y * cs};
  float2 ko = {k.x * cs - k.y * sn, k.x * sn + k.y * cs};
  *(float2*)(Q + base) = qo;
  *(float2*)(K + base) = ko;
}

// ---------------------------------------------------------------------------
// MFMA flash attention (unchanged from R2-fixed version)
// ---------------------------------------------------------------------------
#define KSTRIDE 72

__global__ __launch_bounds__(256)
void attn_mfma(const float* __restrict__ Q, const float* __restrict__ K,
               const float* __restrict__ V, float* __restrict__ O) {
  __shared__ short Ks[64 * KSTRIDE];
  __shared__ short Vt[64 * KSTRIDE];
  __shared__ short Ps[4][16 * KSTRIDE];

  const int tid = threadIdx.x;
  const int w = tid >> 6, lane = tid & 63;
  const int l15 = lane & 15, quad = lane >> 4;
  const int qt = blockIdx.x;
  const int h = blockIdx.y, b = blockIdx.z;
  const size_t bh = (size_t)b * SEQ * D_MODEL + h * DK;
  const int qrow_base = qt * 64 + w * 16;

  bfrag8 qfrag[2];
  {
    const float* qp = Q + bh + (size_t)(qrow_base + l15) * D_MODEL + quad * 8;
    #pragma unroll
    for (int half = 0; half < 2; ++half) {
      float4 v0 = *(const float4*)(qp + half * 32);
      float4 v1 = *(const float4*)(qp + half * 32 + 4);
      short tmp[8];
      tmp[0] = f2bf(v0.x * 0.125f); tmp[1] = f2bf(v0.y * 0.125f);
      tmp[2] = f2bf(v0.z * 0.125f); tmp[3] = f2bf(v0.w * 0.125f);
      tmp[4] = f2bf(v1.x * 0.125f); tmp[5] = f2bf(v1.y * 0.125f);
      tmp[6] = f2bf(v1.z * 0.125f); tmp[7] = f2bf(v1.w * 0.125f);
      qfrag[half] = *(bfrag8*)tmp;
    }
  }

  float m_r[4], l_r[4];
  f32x4 o_acc[4];
  #pragma unroll
  for (int r = 0; r < 4; ++r) { m_r[r] = -1e30f; l_r[r] = 0.f; o_acc[r] = (f32x4)0.f; }

  const int skey = tid >> 2;
  const int sdc  = tid & 3;

  const int ntiles = qt + 1;
  for (int t = 0; t < ntiles; ++t) {
    const int j0 = t * 64;
    __syncthreads();
    {
      const float* kp = K + bh + (size_t)(j0 + skey) * D_MODEL + sdc * 16;
      const float* vp = V + bh + (size_t)(j0 + skey) * D_MODEL + sdc * 16;
      float kf[16], vf[16];
      #pragma unroll
      for (int i = 0; i < 4; ++i) {
        *(float4*)&kf[i * 4] = *(const float4*)(kp + i * 4);
        *(float4*)&vf[i * 4] = *(const float4*)(vp + i * 4);
      }
      short kb[16];
      #pragma unroll
      for (int i = 0; i < 16; ++i) kb[i] = f2bf(kf[i]);
      *(bfrag8*)&Ks[skey * KSTRIDE + sdc * 16]     = *(bfrag8*)&kb[0];
      *(bfrag8*)&Ks[skey * KSTRIDE + sdc * 16 + 8] = *(bfrag8*)&kb[8];
      #pragma unroll
      for (int i = 0; i < 16; ++i)
        Vt[(sdc * 16 + i) * KSTRIDE + skey] = f2bf(vf[i]);
    }
    __syncthreads();

    f32x4 sc[4];
    #pragma unroll
    for (int st = 0; st < 4; ++st) {
      bfrag8 kf0 = *(const bfrag8*)&Ks[(st * 16 + l15) * KSTRIDE + quad * 8];
      bfrag8 kf1 = *(const bfrag8*)&Ks[(st * 16 + l15) * KSTRIDE + 32 + quad * 8];
      f32x4 acc = (f32x4)0.f;
      acc = __builtin_amdgcn_mfma_f32_16x16x32_bf16(qfrag[0], kf0, acc, 0, 0, 0);
      acc = __builtin_amdgcn_mfma_f32_16x16x32_bf16(qfrag[1], kf1, acc, 0, 0, 0);
      sc[st] = acc;
    }

    if (j0 + 64 > qrow_base) {
      #pragma unroll
      for (int st = 0; st < 4; ++st) {
        int key = j0 + st * 16 + l15;
        #pragma unroll
        for (int r = 0; r < 4; ++r) {
          int qrow = qrow_base + quad * 4 + r;
          if (key > qrow) sc[st][r] = -1e30f;
        }
      }
    }

    float p_[4][4];
    #pragma unroll
    for (int r = 0; r < 4; ++r) {
      float tm = fmaxf(fmaxf(sc[0][r], sc[1][r]), fmaxf(sc[2][r], sc[3][r]));
      tm = fmaxf(tm, __shfl_xor(tm, 1));
      tm = fmaxf(tm, __shfl_xor(tm, 2));
      tm = fmaxf(tm, __shfl_xor(tm, 4));
      tm = fmaxf(tm, __shfl_xor(tm, 8));
      float mnew = fmaxf(m_r[r], tm);
      float alpha = __expf(m_r[r] - mnew);
      m_r[r] = mnew;
      float rs = 0.f;
      #pragma unroll
      for (int st = 0; st < 4; ++st) { p_[st][r] = __expf(sc[st][r] - mnew); rs += p_[st][r]; }
      rs += __shfl_xor(rs, 1);
      rs += __shfl_xor(rs, 2);
      rs += __shfl_xor(rs, 4);
      rs += __shfl_xor(rs, 8);
      l_r[r] = l_r[r] * alpha + rs;
      #pragma unroll
      for (int n0 = 0; n0 < 4; ++n0) o_acc[n0][r] *= alpha;
    }

    #pragma unroll
    for (int st = 0; st < 4; ++st)
      #pragma unroll
      for (int r = 0; r < 4; ++r)
        Ps[w][(quad * 4 + r) * KSTRIDE + st * 16 + l15] = f2bf(p_[st][r]);
    __asm__ volatile("s_waitcnt lgkmcnt(0)" ::: "memory");

    #pragma unroll
    for (int kc = 0; kc < 2; ++kc) {
      bfrag8 afrag = *(const bfrag8*)&Ps[w][l15 * KSTRIDE + kc * 32 + quad * 8];
      #pragma unroll
      for (int n0 = 0; n0 < 4; ++n0) {
        bfrag8 vfrag = *(const bfrag8*)&Vt[(n0 * 16 + l15) * KSTRIDE + kc * 32 + quad * 8];
        o_acc[n0] = __builtin_amdgcn_mfma_f32_16x16x32_bf16(afrag, vfrag, o_acc[n0], 0, 0, 0);
      }
    }
  }

  #pragma unroll
  for (int n0 = 0; n0 < 4; ++n0)
    #pragma unroll
    for (int r = 0; r < 4; ++r) {
      int qrow = qrow_base + quad * 4 + r;
      O[bh + (size_t)qrow * D_MODEL + n0 * 16 + l15] = o_acc[n0][r] / l_r[r];
    }
}

// ---------------------------------------------------------------------------
extern "C" void kernel_launch(void* const* d_in, const int* in_sizes, int n_in,
                              void* d_out, int out_size, void* d_ws, size_t ws_size,
                              hipStream_t stream) {
  const float* x  = (const float*)d_in[0];
  const float* Wq = (const float*)d_in[1];
  const float* Wk = (const float*)d_in[2];
  const float* Wv = (const float*)d_in[3];
  const float* Wo = (const float*)d_in[4];
  const int* pos  = (const int*)d_in[5];

  const size_t XSZ = (size_t)MROWS * D_MODEL;   // 4M elems
  const size_t WSZ = (size_t)D_MODEL * D_MODEL; // 1M elems

  float* ws = (float*)d_ws;
  float* Qb = ws;
  float* Kb = ws + XSZ;
  float* Vb = ws + 2 * XSZ;
  float* Ob = ws + 3 * XSZ;
  u16* bfb = (u16*)(ws + 4 * XSZ);   // bf16 region
  u16* xb  = bfb;                    // 4M
  u16* wqb = bfb + XSZ;              // 1M each
  u16* wkb = bfb + XSZ + WSZ;
  u16* wvb = bfb + XSZ + 2 * WSZ;
  u16* wob = bfb + XSZ + 3 * WSZ;
  u16* obb = bfb + XSZ + 4 * WSZ;    // 4M

  // 1. convert x + weights to bf16 (8M elems, float4 per thread)
  CvtPtrs cp; cp.src[0] = x; cp.src[1] = Wq; cp.src[2] = Wk; cp.src[3] = Wv; cp.src[4] = Wo;
  size_t cvtElems = XSZ + 4 * WSZ;               // 8M
  convert_inputs<<<(int)(cvtElems / 4 / 256), 256, 0, stream>>>(cp, xb);

  // 2. fused QKV projection GEMMs (bf16 MFMA), fp32 outputs
  QKVPtrs qp;
  qp.W[0] = wqb; qp.W[1] = wkb; qp.W[2] = wvb;
  qp.C[0] = Qb;  qp.C[1] = Kb;  qp.C[2] = Vb;
  gemm_qkv_bf16<<<dim3(D_MODEL / 128, MROWS / 128, 3), 256, 0, stream>>>(xb, qp);

  // 3. RoPE
  int totalPairs = BATCH * SEQ * NHEADS * (DK / 2);
  rope_kernel<<<(totalPairs + 255) / 256, 256, 0, stream>>>(Qb, Kb, pos, totalPairs);

  // 4. flash attention
  attn_mfma<<<dim3(SEQ / 64, NHEADS, BATCH), 256, 0, stream>>>(Qb, Kb, Vb, Ob);

  // 5. convert attention output to bf16
  convert_buf<<<(int)(XSZ / 4 / 256), 256, 0, stream>>>(Ob, obb);

  // 6. output projection
  gemm_out_bf16<<<dim3(D_MODEL / 128, MROWS / 128), 256, 0, stream>>>(obb, wob, (float*)d_out);
}

// Round 5
// 240.935 us; speedup vs baseline: 7.2654x; 1.3346x over previous
//
#include <hip/hip_runtime.h>
#include <math.h>

#define D_MODEL 1024
#define NHEADS 16
#define DK 64
#define SEQ 2048
#define BATCH 2
#define MROWS (BATCH * SEQ)            // 4096

typedef __attribute__((ext_vector_type(8))) short bfrag8;   // 8 bf16 (4 VGPRs)
typedef __attribute__((ext_vector_type(4))) float f32x4;
typedef unsigned short u16;
typedef __attribute__((ext_vector_type(8))) u16 u16x8;
typedef __attribute__((ext_vector_type(4))) u16 u16x4;

#define GLOBAL_AS(p) ((const __attribute__((address_space(1))) void*)(p))
#define LDS_AS(p)    ((__attribute__((address_space(3))) void*)(p))

__device__ inline u16 f2bf(float f) {
  union { float f; unsigned u; } c; c.f = f;
  unsigned r = c.u + 0x7FFF + ((c.u >> 16) & 1);   // RNE
  return (u16)(r >> 16);
}

// ---------------------------------------------------------------------------
// fp32 -> bf16 conversion for x + the 4 weights (contiguous dst region).
// ---------------------------------------------------------------------------
struct CvtPtrs { const float* src[5]; };

__global__ __launch_bounds__(256)
void convert_inputs(CvtPtrs p, u16* __restrict__ dst) {
  size_t base = ((size_t)blockIdx.x * 256 + threadIdx.x) * 4;
  const size_t XSZ = (size_t)MROWS * D_MODEL;              // 4M
  const float* s; size_t off;
  if (base < XSZ) { s = p.src[0]; off = base; }
  else {
    size_t j = base - XSZ;
    s = p.src[1 + (int)(j >> 20)];
    off = j & ((1u << 20) - 1);
  }
  float4 v = *(const float4*)(s + off);
  u16 o[4] = { f2bf(v.x), f2bf(v.y), f2bf(v.z), f2bf(v.w) };
  *(u16x4*)(dst + base) = *(u16x4*)o;
}

// ---------------------------------------------------------------------------
// bf16 MFMA NT-GEMM (m97 structure) — unchanged from R4.
// ---------------------------------------------------------------------------
__device__ inline void gemm_tile_body(const u16* __restrict__ A,
                                      const u16* __restrict__ B,
                                      float* __restrict__ C,
                                      int m0, int n0) {
  __shared__ u16 As[128 * 32];
  __shared__ u16 Bs[128 * 32];

  const int tid = threadIdx.x;
  const int w = tid >> 6, lane = tid & 63;
  const int l15 = lane & 15, quad = lane >> 4;
  const int wm = w >> 1, wn = w & 1;
  const int srow = tid >> 2;
  const int scol = (tid & 3) * 8;

  f32x4 acc[4][4];
  #pragma unroll
  for (int mi = 0; mi < 4; ++mi)
    #pragma unroll
    for (int ni = 0; ni < 4; ++ni) acc[mi][ni] = (f32x4)0.f;

  for (int k0 = 0; k0 < D_MODEL; k0 += 32) {
    __syncthreads();
    #pragma unroll
    for (int i = 0; i < 2; ++i) {
      const u16* ga = A + (size_t)((i * 64 + srow) + m0) * D_MODEL + k0 + scol;
      const u16* gb = B + (size_t)((i * 64 + srow) + n0) * D_MODEL + k0 + scol;
      __builtin_amdgcn_global_load_lds(GLOBAL_AS(ga), LDS_AS(&As[(i * 64 + w * 16) * 32]), 16, 0, 0);
      __builtin_amdgcn_global_load_lds(GLOBAL_AS(gb), LDS_AS(&Bs[(i * 64 + w * 16) * 32]), 16, 0, 0);
    }
    __syncthreads();

    bfrag8 af[4], bfr[4];
    #pragma unroll
    for (int i = 0; i < 4; ++i) {
      af[i]  = *(const bfrag8*)&As[(wm * 64 + i * 16 + l15) * 32 + quad * 8];
      bfr[i] = *(const bfrag8*)&Bs[(wn * 64 + i * 16 + l15) * 32 + quad * 8];
    }
    #pragma unroll
    for (int mi = 0; mi < 4; ++mi)
      #pragma unroll
      for (int ni = 0; ni < 4; ++ni)
        acc[mi][ni] = __builtin_amdgcn_mfma_f32_16x16x32_bf16(af[mi], bfr[ni], acc[mi][ni], 0, 0, 0);
  }

  #pragma unroll
  for (int mi = 0; mi < 4; ++mi)
    #pragma unroll
    for (int ni = 0; ni < 4; ++ni)
      #pragma unroll
      for (int r = 0; r < 4; ++r) {
        int row = m0 + wm * 64 + mi * 16 + quad * 4 + r;
        int col = n0 + wn * 64 + ni * 16 + l15;
        C[(size_t)row * D_MODEL + col] = acc[mi][ni][r];
      }
}

struct QKVPtrs { const u16* W[3]; float* C[3]; };

__global__ __launch_bounds__(256)
void gemm_qkv_bf16(const u16* __restrict__ A, QKVPtrs p) {
  gemm_tile_body(A, p.W[blockIdx.z], p.C[blockIdx.z],
                 blockIdx.y * 128, blockIdx.x * 128);
}

__global__ __launch_bounds__(256)
void gemm_out_bf16(const u16* __restrict__ A, const u16* __restrict__ B,
                   float* __restrict__ C) {
  gemm_tile_body(A, B, C, blockIdx.y * 128, blockIdx.x * 128);
}

// ---------------------------------------------------------------------------
// prep: fused RoPE + bf16 cast + per-head repack.
//   Qbf[b,h,s,64] = rope(Q)*0.125 bf16 ; Kbf[b,h,s,64] = rope(K) bf16
//   Vtb[b,h,64,s] = V^T bf16 (LDS transpose, XOR-swizzled rows)
// grid (SEQ/128, H, B), 256 threads. thread = (row r=tid>>1, half hf=tid&1).
// ---------------------------------------------------------------------------
__global__ __launch_bounds__(256)
void prep_qkv(const float* __restrict__ Qf, const float* __restrict__ Kf,
              const float* __restrict__ Vf, const int* __restrict__ pos,
              u16* __restrict__ Qbf, u16* __restrict__ Kbf, u16* __restrict__ Vtb) {
  __shared__ u16 Vls[128 * 64];       // row stride 64, chunk-XOR-swizzled

  const int tid = threadIdx.x;
  const int s0 = blockIdx.x * 128;
  const int h = blockIdx.y, b = blockIdx.z;
  const int r = tid >> 1, hf = tid & 1;
  const int s = s0 + r;
  const size_t inoff = ((size_t)(b * SEQ + s)) * D_MODEL + h * DK + hf * 32;
  const size_t ho = ((size_t)(b * NHEADS + h)) * SEQ * DK;

  float qv[32], kv[32], vv[32];
  #pragma unroll
  for (int i = 0; i < 8; ++i) {
    *(float4*)&qv[i * 4] = *(const float4*)(Qf + inoff + i * 4);
    *(float4*)&kv[i * 4] = *(const float4*)(Kf + inoff + i * 4);
    *(float4*)&vv[i * 4] = *(const float4*)(Vf + inoff + i * 4);
  }

  float p = (float)pos[b * SEQ + s];
  alignas(16) u16 qo[32], ko[32], vo[32];
  #pragma unroll
  for (int il = 0; il < 16; ++il) {
    int i = hf * 16 + il;
    float freq = expf(-(float)i * 0.2878231366242558f);   // 10000^(-i/32)
    float sn, cs;
    sincosf(p * freq, &sn, &cs);
    float qe = qv[2 * il], qd = qv[2 * il + 1];
    float ke = kv[2 * il], kd = kv[2 * il + 1];
    qo[2 * il]     = f2bf((qe * cs - qd * sn) * 0.125f);
    qo[2 * il + 1] = f2bf((qe * sn + qd * cs) * 0.125f);
    ko[2 * il]     = f2bf(ke * cs - kd * sn);
    ko[2 * il + 1] = f2bf(ke * sn + kd * cs);
  }
  #pragma unroll
  for (int j = 0; j < 32; ++j) vo[j] = f2bf(vv[j]);

  u16* qdst = Qbf + ho + (size_t)s * DK + hf * 32;
  u16* kdst = Kbf + ho + (size_t)s * DK + hf * 32;
  #pragma unroll
  for (int c = 0; c < 4; ++c) {
    *(u16x8*)(qdst + c * 8) = *(u16x8*)(qo + c * 8);
    *(u16x8*)(kdst + c * 8) = *(u16x8*)(ko + c * 8);
  }
  // V -> LDS with row-dependent chunk swizzle (breaks 128B-wrap conflicts)
  #pragma unroll
  for (int c = 0; c < 4; ++c) {
    int cc = hf * 4 + c;
    int swz = (r + (r >> 5)) & 7;
    *(u16x8*)&Vls[r * 64 + ((cc ^ swz) * 8)] = *(u16x8*)(vo + c * 8);
  }
  __syncthreads();
  // transpose out: thread = (dim = tid>>2, 32-seq chunk)
  {
    const int dim = tid >> 2, sc = (tid & 3) * 32;
    alignas(16) u16 orow[32];
    #pragma unroll
    for (int j = 0; j < 32; ++j) {
      int srow = sc + j;
      int swz = (srow + (srow >> 5)) & 7;
      orow[j] = Vls[srow * 64 + (((dim >> 3) ^ swz) * 8) + (dim & 7)];
    }
    u16* vdst = Vtb + ho + (size_t)dim * SEQ + s0 + sc;
    #pragma unroll
    for (int c = 0; c < 4; ++c)
      *(u16x8*)(vdst + c * 8) = *(u16x8*)(orow + c * 8);
  }
}

// ---------------------------------------------------------------------------
// Transposed-score MFMA flash attention.
// Grid (16,16,2), 256 threads (4 waves). Block owns 128 q-rows (wave: 32 = 2
// sets of 16). S^T = K·Q^T so softmax rows sit on l15; P written as b64 rows
// [q][key]; O^T = V^T·P. K/V staged via global_load_lds with XOR chunk
// swizzle (conflict-free b128 frag reads, no padding needed).
// qt folded by (h^b) parity for load balance.
// ---------------------------------------------------------------------------
#define PSTR 72

__global__ __launch_bounds__(256)
void attn_mfma(const u16* __restrict__ Qbf, const u16* __restrict__ Kbf,
               const u16* __restrict__ Vtb, u16* __restrict__ obb) {
  __shared__ u16 Ks[64 * 64];
  __shared__ u16 Vt[64 * 64];
  __shared__ u16 Ps[4][2][16 * PSTR];

  const int tid = threadIdx.x;
  const int w = tid >> 6, lane = tid & 63;
  const int l15 = lane & 15, quad = lane >> 4;
  const int h = blockIdx.y, b = blockIdx.z;
  const int qt = ((h ^ b) & 1) ? (15 - blockIdx.x) : blockIdx.x;
  const int q0 = qt * 128;
  const size_t ho = ((size_t)(b * NHEADS + h)) * SEQ * DK;
  const int base_w = q0 + w * 32;

  // Q B-frags (rope'd, pre-scaled bf16), loaded once.
  bfrag8 qf[2][2];
  #pragma unroll
  for (int s = 0; s < 2; ++s)
    #pragma unroll
    for (int hh = 0; hh < 2; ++hh)
      qf[s][hh] = *(const bfrag8*)&Qbf[ho + (size_t)(base_w + s * 16 + l15) * DK + hh * 32 + quad * 8];

  f32x4 oacc[2][4];
  float m_[2] = {-1e30f, -1e30f}, l_[2] = {0.f, 0.f};
  #pragma unroll
  for (int s = 0; s < 2; ++s)
    #pragma unroll
    for (int n0 = 0; n0 < 4; ++n0) oacc[s][n0] = (f32x4)0.f;

  const int ntiles = 2 * qt + 2;
  for (int t = 0; t < ntiles; ++t) {
    const int j0 = t * 64;
    __syncthreads();
    // ---- stage K[64key][64dim] and Vt[64dim][64key], XOR-swizzled chunks ----
    #pragma unroll
    for (int i = 0; i < 2; ++i) {
      int row = i * 32 + w * 8 + (lane >> 3);     // key for Ks, dim for Vt
      int cp = lane & 7;
      int c = cp ^ (row & 7);
      const u16* ksrc = Kbf + ho + (size_t)(j0 + row) * DK + c * 8;
      const u16* vsrc = Vtb + ho + (size_t)row * SEQ + j0 + c * 8;
      __builtin_amdgcn_global_load_lds(GLOBAL_AS(ksrc), LDS_AS(&Ks[(i * 4 + w) * 512]), 16, 0, 0);
      __builtin_amdgcn_global_load_lds(GLOBAL_AS(vsrc), LDS_AS(&Vt[(i * 4 + w) * 512]), 16, 0, 0);
    }
    __syncthreads();

    if (j0 > base_w + 31) continue;   // wave fully above diagonal: all masked

    // ---- S^T = K·Q^T : A-frag = K rows, B-frag = Q rows ----
    f32x4 sc[2][4];
    #pragma unroll
    for (int st = 0; st < 4; ++st) {
      int key = st * 16 + l15;
      int sw = l15 & 7;
      bfrag8 kf0 = *(const bfrag8*)&Ks[key * 64 + ((quad ^ sw) * 8)];
      bfrag8 kf1 = *(const bfrag8*)&Ks[key * 64 + (((4 + quad) ^ sw) * 8)];
      sc[0][st] = __builtin_amdgcn_mfma_f32_16x16x32_bf16(kf0, qf[0][0], (f32x4)0.f, 0, 0, 0);
      sc[0][st] = __builtin_amdgcn_mfma_f32_16x16x32_bf16(kf1, qf[0][1], sc[0][st], 0, 0, 0);
      sc[1][st] = __builtin_amdgcn_mfma_f32_16x16x32_bf16(kf0, qf[1][0], (f32x4)0.f, 0, 0, 0);
      sc[1][st] = __builtin_amdgcn_mfma_f32_16x16x32_bf16(kf1, qf[1][1], sc[1][st], 0, 0, 0);
    }

    // ---- per-set: mask, online softmax (row = q = l15), write P ----
    #pragma unroll
    for (int s = 0; s < 2; ++s) {
      const int qb = base_w + s * 16;
      if (j0 + 63 > qb) {
        #pragma unroll
        for (int st = 0; st < 4; ++st)
          #pragma unroll
          for (int r = 0; r < 4; ++r) {
            int key = j0 + st * 16 + quad * 4 + r;
            if (key > qb + l15) sc[s][st][r] = -1e30f;
          }
      }
      float mx = sc[s][0][0];
      #pragma unroll
      for (int st = 0; st < 4; ++st)
        #pragma unroll
        for (int r = 0; r < 4; ++r) mx = fmaxf(mx, sc[s][st][r]);
      mx = fmaxf(mx, __shfl_xor(mx, 16));
      mx = fmaxf(mx, __shfl_xor(mx, 32));
      float mnew = fmaxf(m_[s], mx);
      float alpha = __expf(m_[s] - mnew);
      m_[s] = mnew;
      float pv[4][4], rs = 0.f;
      #pragma unroll
      for (int st = 0; st < 4; ++st)
        #pragma unroll
        for (int r = 0; r < 4; ++r) { pv[st][r] = __expf(sc[s][st][r] - mnew); rs += pv[st][r]; }
      rs += __shfl_xor(rs, 16);
      rs += __shfl_xor(rs, 32);
      l_[s] = l_[s] * alpha + rs;
      #pragma unroll
      for (int n0 = 0; n0 < 4; ++n0) oacc[s][n0] *= alpha;
      #pragma unroll
      for (int st = 0; st < 4; ++st) {
        u16x4 pk = { f2bf(pv[st][0]), f2bf(pv[st][1]), f2bf(pv[st][2]), f2bf(pv[st][3]) };
        *(u16x4*)&Ps[w][s][l15 * PSTR + st * 16 + quad * 4] = pk;
      }
    }
    __asm__ volatile("s_waitcnt lgkmcnt(0)" ::: "memory");

    // ---- O^T += V^T·P : A-frag = Vt rows, B-frag = Ps rows ----
    bfrag8 pf[2][2];
    #pragma unroll
    for (int s = 0; s < 2; ++s)
      #pragma unroll
      for (int kc = 0; kc < 2; ++kc)
        pf[s][kc] = *(const bfrag8*)&Ps[w][s][l15 * PSTR + kc * 32 + quad * 8];
    #pragma unroll
    for (int n0 = 0; n0 < 4; ++n0) {
      int sw = l15 & 7;
      #pragma unroll
      for (int kc = 0; kc < 2; ++kc) {
        bfrag8 vf = *(const bfrag8*)&Vt[(n0 * 16 + l15) * 64 + (((kc * 4 + quad) ^ sw) * 8)];
        oacc[0][n0] = __builtin_amdgcn_mfma_f32_16x16x32_bf16(vf, pf[0][kc], oacc[0][n0], 0, 0, 0);
        oacc[1][n0] = __builtin_amdgcn_mfma_f32_16x16x32_bf16(vf, pf[1][kc], oacc[1][n0], 0, 0, 0);
      }
    }
  }

  // ---- epilogue: O^T[dim][q] -> obb[b*S+q][h*64+dim] bf16, /l ----
  #pragma unroll
  for (int s = 0; s < 2; ++s) {
    float inv = 1.f / l_[s];
    int q = base_w + s * 16 + l15;
    #pragma unroll
    for (int n0 = 0; n0 < 4; ++n0) {
      u16x4 ov = { f2bf(oacc[s][n0][0] * inv), f2bf(oacc[s][n0][1] * inv),
                   f2bf(oacc[s][n0][2] * inv), f2bf(oacc[s][n0][3] * inv) };
      *(u16x4*)&obb[(size_t)(b * SEQ + q) * D_MODEL + h * DK + n0 * 16 + quad * 4] = ov;
    }
  }
}

// ---------------------------------------------------------------------------
extern "C" void kernel_launch(void* const* d_in, const int* in_sizes, int n_in,
                              void* d_out, int out_size, void* d_ws, size_t ws_size,
                              hipStream_t stream) {
  const float* x  = (const float*)d_in[0];
  const float* Wq = (const float*)d_in[1];
  const float* Wk = (const float*)d_in[2];
  const float* Wv = (const float*)d_in[3];
  const float* Wo = (const float*)d_in[4];
  const int* pos  = (const int*)d_in[5];

  const size_t XSZ = (size_t)MROWS * D_MODEL;   // 4M elems
  const size_t WSZ = (size_t)D_MODEL * D_MODEL; // 1M elems

  float* ws = (float*)d_ws;
  float* Qf = ws;                     // 4M fp32 (dead after prep; obb overlays)
  float* Kf = ws + XSZ;
  float* Vf = ws + 2 * XSZ;
  u16* bfb = (u16*)(ws + 3 * XSZ);
  u16* xb  = bfb;                     // 4M
  u16* wqb = bfb + XSZ;
  u16* wkb = bfb + XSZ + WSZ;
  u16* wvb = bfb + XSZ + 2 * WSZ;
  u16* wob = bfb + XSZ + 3 * WSZ;
  u16* Qbf = bfb + XSZ + 4 * WSZ;     // 4M
  u16* Kbf = Qbf + XSZ;               // 4M
  u16* Vtb = Kbf + XSZ;               // 4M
  u16* obb = (u16*)Qf;                // overlays Qf (safe: prep before attn)

  // 1. convert x + weights to bf16
  CvtPtrs cp; cp.src[0] = x; cp.src[1] = Wq; cp.src[2] = Wk; cp.src[3] = Wv; cp.src[4] = Wo;
  size_t cvtElems = XSZ + 4 * WSZ;    // 8M
  convert_inputs<<<(int)(cvtElems / 4 / 256), 256, 0, stream>>>(cp, xb);

  // 2. QKV projections (bf16 MFMA), fp32 out
  QKVPtrs qp;
  qp.W[0] = wqb; qp.W[1] = wkb; qp.W[2] = wvb;
  qp.C[0] = Qf;  qp.C[1] = Kf;  qp.C[2] = Vf;
  gemm_qkv_bf16<<<dim3(D_MODEL / 128, MROWS / 128, 3), 256, 0, stream>>>(xb, qp);

  // 3. RoPE + cast + repack (+ V transpose)
  prep_qkv<<<dim3(SEQ / 128, NHEADS, BATCH), 256, 0, stream>>>(Qf, Kf, Vf, pos, Qbf, Kbf, Vtb);

  // 4. flash attention -> bf16 obb
  attn_mfma<<<dim3(SEQ / 128, NHEADS, BATCH), 256, 0, stream>>>(Qbf, Kbf, Vtb, obb);

  // 5. output projection
  gemm_out_bf16<<<dim3(D_MODEL / 128, MROWS / 128), 256, 0, stream>>>(obb, wob, (float*)d_out);
}